// Round 5
// baseline (820.542 us; speedup 1.0000x reference)
//
#include <hip/hip_runtime.h>

typedef unsigned int uint;

#define N_NODES 1000000
#define D       128
#define T_STEPS 100
#define B       1024
#define K       6
#define ALPHA   0.025f

// persistent loop kernel: 64 blocks x 1024 threads = 1024 waves = B edges
#define LNBLK  64
#define LTPB   1024
#define NGRP   8
#define GRPSZ  8                   // LNBLK / NGRP

// ws layout (uint granularity), all counter lines 128B-strided:
//   root[k]   at k*32,                 k < 256   -> 32 KB
//   grp[k][g] at GRP_OFF + (k*8+g)*32            -> 208 KB
//   flags[r]  at FLAG_OFF (N_NODES uints = 4 MB, SPARSE only)
#define GRP_OFF      8192
#define FLAG_OFF     65536
#define CNT_BYTES    ((size_t)FLAG_OFF * 4)              // 256 KB (< 512 KB proven)
#define SPARSE_BYTES ((size_t)(FLAG_OFF + N_NODES) * 4)  // ~4.26 MB (ws fits: proven r2-r4)

__device__ __forceinline__ float wave_sum(float v) {
#pragma unroll
    for (int off = 32; off; off >>= 1) v += __shfl_xor(v, off, 64);
    return v;
}

// 8-byte agent-scope atomic load: served at the coherent point (LLC), immune to
// stale per-XCD L2 lines. Used for all rows mutated by atomicAdd scatters.
__device__ __forceinline__ float2 aload8(const float* p) {
    unsigned long long v = __hip_atomic_load((const unsigned long long*)p,
                                             __ATOMIC_RELAXED,
                                             __HIP_MEMORY_SCOPE_AGENT);
    union { unsigned long long u; float2 f; } c; c.u = v;
    return c.f;
}

// Split-phase fence-free TWO-LEVEL grid barrier.
//  - fence-free validity (r3/r4-proven): every cross-block datum moves via
//    device-scope atomics executed at the LLC; nothing dirty to publish,
//    nothing stale to invalidate.
//  - TREE arrival: r4's single root line serialized 64 RMWs (~100cy each =
//    2.7us, the measured barrier cost). 8 group lines x 8 arrivals run in
//    parallel (~0.35us), group closers feed an 8-deep root chain.
//  - arrive(): __syncthreads drains each thread's vmcnt(0) (compiler emits the
//    full s_waitcnt before s_barrier), so the block's gathers/scatter-atomics
//    are complete at the LLC before thread0 signals.
//  - Each rendezvous k uses its own pre-zeroed slots -> replay-deterministic.
__device__ __forceinline__ void bar_arrive(uint* ws_u, int k) {
    __syncthreads();
    if (threadIdx.x == 0) {
        const uint g = (uint)blockIdx.x & (NGRP - 1);
        uint* grpc = &ws_u[GRP_OFF + (k * NGRP + (int)g) * 32];
        if (atomicAdd(grpc, 1u) == GRPSZ - 1u)
            atomicAdd(&ws_u[k * 32], 1u);
    }
}
__device__ __forceinline__ void bar_wait(uint* ws_u, int k) {
    if (threadIdx.x == 0) {
        while (__hip_atomic_load(&ws_u[k * 32], __ATOMIC_RELAXED,
                                 __HIP_MEMORY_SCOPE_AGENT) < (uint)NGRP)
            __builtin_amdgcn_s_sleep(1);
    }
    __syncthreads();
}

// ---------------- prologue: flags + materialize mutable rows in `out` ----------
template <bool SPARSE>
__global__ __launch_bounds__(256) void prologue(const float* __restrict__ emb_in,
                                                const int*   __restrict__ u_idx, // [T*B]
                                                float*       __restrict__ out,
                                                uint*        __restrict__ flags)
{
    if (SPARSE) {
        const int wave = (blockIdx.x * 256 + threadIdx.x) >> 6;
        const int lane = threadIdx.x & 63;
        const int nw = gridDim.x * 4;
        for (int e = wave; e < T_STEPS * B; e += nw) {
            const int r = u_idx[e];
            if (lane == 0) flags[r] = 1u;            // dups write identical bytes
            const size_t off = (size_t)r * D + 2 * lane;
            *(float2*)(out + off) = *(const float2*)(emb_in + off);
        }
    } else {
        const int tid = blockIdx.x * 256 + threadIdx.x;
        const int stride = gridDim.x * 256;
        const float4* src = (const float4*)emb_in;
        float4*       dst = (float4*)out;
        for (int i = tid; i < N_NODES * D / 4; i += stride) dst[i] = src[i];
    }
}

// ---------------- persistent SGD loop: 100 steps, split-phase tree barriers ----
template <bool SPARSE>
__global__ __launch_bounds__(LTPB) void line_loop(const float* __restrict__ emb_in,
                                                  const int*   __restrict__ u_idx,   // [T*B]
                                                  const int*   __restrict__ tgt_idx, // [T*B*K]
                                                  float*       __restrict__ out,
                                                  uint*        ws_u)
{
    const int wave = (blockIdx.x * LTPB + threadIdx.x) >> 6; // 0..1023 == edge b
    const int lane = threadIdx.x & 63;
    const uint* flags = ws_u + FLAG_OFF;  // immutable here -> plain cached loads
    const int b = wave;

    int  cu, cv[K];
    uint fv[K];
    cu = u_idx[b];
#pragma unroll
    for (int k = 0; k < K; ++k) cv[k] = tgt_idx[b * K + k];
#pragma unroll
    for (int k = 0; k < K; ++k) fv[k] = SPARSE ? flags[cv[k]] : 1u;

    float2 v2[K];
    // step-0 immutable gathers (emb_in never written -> any cache OK)
#pragma unroll
    for (int k = 0; k < K; ++k)
        if (!fv[k]) v2[k] = *(const float2*)(emb_in + (size_t)cv[k] * D + 2 * lane);

    for (int t = 0; t < T_STEPS; ++t) {
        // mutable gathers: LLC-coherent, see state after step t-1's barrier B
        float2 u2 = aload8(out + (size_t)cu * D + 2 * lane);
#pragma unroll
        for (int k = 0; k < K; ++k)
            if (fv[k]) v2[k] = aload8(out + (size_t)cv[k] * D + 2 * lane);

        // next-step index/flag loads issue here, overlapping gather latency
        int  ncu = 0, ncv[K];
        uint nfv[K];
        if (t + 1 < T_STEPS) {
            const int nb = (t + 1) * B + b;
            ncu = u_idx[nb];
#pragma unroll
            for (int k = 0; k < K; ++k) ncv[k] = tgt_idx[nb * K + k];
#pragma unroll
            for (int k = 0; k < K; ++k) nfv[k] = SPARSE ? flags[ncv[k]] : 1u;
        } else {
#pragma unroll
            for (int k = 0; k < K; ++k) { ncv[k] = 0; nfv[k] = 1u; }
        }

        bar_arrive(ws_u, 2 * t);           // signals: my gathers are complete

        // err = sum_k g_k * v_k -- pure register work, hides rendezvous A
        float2 e2 = make_float2(0.f, 0.f);
#pragma unroll
        for (int k = 0; k < K; ++k) {
            const float s = wave_sum(u2.x * v2[k].x + u2.y * v2[k].y);
            const float f = 1.f / (1.f + __expf(-s));
            const float g = ALPHA * ((k == 0 ? 1.f : 0.f) - f);
            e2.x += g * v2[k].x;
            e2.y += g * v2[k].y;
        }

        bar_wait(ws_u, 2 * t);             // all gathers of step t done grid-wide

        float* urow = out + (size_t)cu * D + 2 * lane;
        atomicAdd(urow,     e2.x);         // RMW at LLC -> coherent
        atomicAdd(urow + 1, e2.y);

        if (t + 1 < T_STEPS) {
            bar_arrive(ws_u, 2 * t + 1);   // syncthreads drained the scatters
            // next step's immutable gathers hide rendezvous B
#pragma unroll
            for (int k = 0; k < K; ++k)
                if (!nfv[k]) v2[k] = *(const float2*)(emb_in + (size_t)ncv[k] * D + 2 * lane);
            bar_wait(ws_u, 2 * t + 1);     // all scatters of step t at LLC
        }
        // last step: kernel boundary is the barrier before normalize_k

        cu = ncu;
#pragma unroll
        for (int k = 0; k < K; ++k) { cv[k] = ncv[k]; fv[k] = nfv[k]; }
    }
}

// ---------------- final L2 row-normalize: full-BW streaming kernel -------------
template <bool SPARSE>
__global__ __launch_bounds__(256) void normalize_k(const float* __restrict__ emb_in,
                                                   float*       __restrict__ out,
                                                   const uint*  __restrict__ flags)
{
    const int wave = (blockIdx.x * 256 + threadIdx.x) >> 6;
    const int lane = threadIdx.x & 63;
    const int nw = gridDim.x * 4;
    for (int r0 = wave * 4; r0 < N_NODES; r0 += nw * 4) {
        uint4 f4 = SPARSE ? *(const uint4*)(flags + r0) : make_uint4(1u, 1u, 1u, 1u);
        const uint fl[4] = { f4.x, f4.y, f4.z, f4.w };
        float2 v[4];
#pragma unroll
        for (int j = 0; j < 4; ++j) {
            const float* src = fl[j] ? out : emb_in;   // wave-uniform branch
            v[j] = *(const float2*)(src + (size_t)(r0 + j) * D + 2 * lane);
        }
#pragma unroll
        for (int j = 0; j < 4; ++j) {
            const float ss  = wave_sum(v[j].x * v[j].x + v[j].y * v[j].y);
            const float inv = 1.f / fmaxf(sqrtf(ss), 1e-12f);
            *(float2*)(out + (size_t)(r0 + j) * D + 2 * lane) =
                make_float2(v[j].x * inv, v[j].y * inv);
        }
    }
}

extern "C" void kernel_launch(void* const* d_in, const int* in_sizes, int n_in,
                              void* d_out, int out_size, void* d_ws, size_t ws_size,
                              hipStream_t stream)
{
    const float* emb_in  = (const float*)d_in[0];
    const int*   u_idx   = (const int*)d_in[1];
    const int*   tgt_idx = (const int*)d_in[2];
    float*       out     = (float*)d_out;
    uint*        ws_u    = (uint*)d_ws;
    uint*        flags   = ws_u + FLAG_OFF;

    const bool sparse = ws_size >= SPARSE_BYTES;
    hipMemsetAsync(d_ws, 0, sparse ? SPARSE_BYTES : CNT_BYTES, stream);

    if (sparse) {
        prologue<true>  <<<1024, 256, 0, stream>>>(emb_in, u_idx, out, flags);
        line_loop<true> <<<LNBLK, LTPB, 0, stream>>>(emb_in, u_idx, tgt_idx, out, ws_u);
        normalize_k<true> <<<2048, 256, 0, stream>>>(emb_in, out, flags);
    } else {
        prologue<false>  <<<2048, 256, 0, stream>>>(emb_in, u_idx, out, flags);
        line_loop<false> <<<LNBLK, LTPB, 0, stream>>>(emb_in, u_idx, tgt_idx, out, ws_u);
        normalize_k<false> <<<2048, 256, 0, stream>>>(emb_in, out, flags);
    }
}

// Round 6
// 734.312 us; speedup vs baseline: 1.1174x; 1.1174x over previous
//
#include <hip/hip_runtime.h>

typedef unsigned int uint;

#define N_NODES 1000000
#define D       128
#define T_STEPS 100
#define B       1024
#define K       6
#define ALPHA   0.025f

// persistent loop kernel: 64 blocks x 1024 threads = 1024 waves = B edges
#define LNBLK  64
#define LTPB   1024

// ws layout (uint granularity):
//   barrier flags: word k*64 + block,  k < 256  -> 64 KB used, 256 KB reserved
//   flags[r] at FLAG_OFF (N_NODES uints = 4 MB, SPARSE only)
#define FLAG_OFF     65536
#define CNT_BYTES    ((size_t)FLAG_OFF * 4)              // 256 KB (< 512 KB proven)
#define SPARSE_BYTES ((size_t)(FLAG_OFF + N_NODES) * 4)  // ~4.26 MB (ws fits: proven r2-r5)

__device__ __forceinline__ float wave_sum(float v) {
#pragma unroll
    for (int off = 32; off; off >>= 1) v += __shfl_xor(v, off, 64);
    return v;
}

// 8-byte agent-scope atomic load: served at the coherent point (LLC), immune to
// stale per-XCD L2 lines. Used for all rows mutated by atomicAdd scatters.
__device__ __forceinline__ float2 aload8(const float* p) {
    unsigned long long v = __hip_atomic_load((const unsigned long long*)p,
                                             __ATOMIC_RELAXED,
                                             __HIP_MEMORY_SCOPE_AGENT);
    union { unsigned long long u; float2 f; } c; c.u = v;
    return c.f;
}

// Split-phase fence-free ALL-TO-ALL grid barrier (single LLC hop).
//  - fence-free validity (r3-r5 proven): every cross-block datum moves via
//    device-scope atomics executed at the LLC; nothing dirty to publish,
//    nothing stale to invalidate.
//  - r4 (single root line) and r5 (tree) were NOTIFY-CHAIN bound: 2-3
//    dependent LLC round trips after the last arrival. Here: arrival is one
//    RMW to the block's OWN word (zero cross-block serialization); waiters
//    are wave 0's 64 lanes each spinning on one block's word -> one poll
//    round trip after the last arrival lands.
//  - arrive(): __syncthreads drains each thread's vmcnt(0) (compiler emits
//    the full s_waitcnt before s_barrier), so the block's gathers/scatter-
//    atomics are complete at the LLC before thread0 signals.
//  - Each rendezvous k uses its own pre-zeroed 64-word slot -> replay-clean.
__device__ __forceinline__ void bar_arrive(uint* ws_u, int k) {
    __syncthreads();
    if (threadIdx.x == 0)
        atomicAdd(&ws_u[k * 64 + (int)blockIdx.x], 1u);
}
__device__ __forceinline__ void bar_wait(uint* ws_u, int k) {
    if (threadIdx.x < 64) {        // wave 0: lane j watches block j's word
        while (__hip_atomic_load(&ws_u[k * 64 + (int)threadIdx.x],
                                 __ATOMIC_RELAXED,
                                 __HIP_MEMORY_SCOPE_AGENT) == 0u) { }
    }
    __syncthreads();
}

// ---------------- prologue: flags + materialize mutable rows in `out` ----------
template <bool SPARSE>
__global__ __launch_bounds__(256) void prologue(const float* __restrict__ emb_in,
                                                const int*   __restrict__ u_idx, // [T*B]
                                                float*       __restrict__ out,
                                                uint*        __restrict__ flags)
{
    if (SPARSE) {
        const int wave = (blockIdx.x * 256 + threadIdx.x) >> 6;
        const int lane = threadIdx.x & 63;
        const int nw = gridDim.x * 4;
        for (int e = wave; e < T_STEPS * B; e += nw) {
            const int r = u_idx[e];
            if (lane == 0) flags[r] = 1u;            // dups write identical bytes
            const size_t off = (size_t)r * D + 2 * lane;
            *(float2*)(out + off) = *(const float2*)(emb_in + off);
        }
    } else {
        const int tid = blockIdx.x * 256 + threadIdx.x;
        const int stride = gridDim.x * 256;
        const float4* src = (const float4*)emb_in;
        float4*       dst = (float4*)out;
        for (int i = tid; i < N_NODES * D / 4; i += stride) dst[i] = src[i];
    }
}

// ---------------- persistent SGD loop: 100 steps, split-phase a2a barriers -----
template <bool SPARSE>
__global__ __launch_bounds__(LTPB) void line_loop(const float* __restrict__ emb_in,
                                                  const int*   __restrict__ u_idx,   // [T*B]
                                                  const int*   __restrict__ tgt_idx, // [T*B*K]
                                                  float*       __restrict__ out,
                                                  uint*        ws_u)
{
    const int wave = (blockIdx.x * LTPB + threadIdx.x) >> 6; // 0..1023 == edge b
    const int lane = threadIdx.x & 63;
    const uint* flags = ws_u + FLAG_OFF;  // immutable here -> plain cached loads
    const int b = wave;

    int  cu, cv[K];
    uint fv[K];
    cu = u_idx[b];
#pragma unroll
    for (int k = 0; k < K; ++k) cv[k] = tgt_idx[b * K + k];
#pragma unroll
    for (int k = 0; k < K; ++k) fv[k] = SPARSE ? flags[cv[k]] : 1u;

    float2 v2[K];
    // step-0 immutable gathers (emb_in never written -> any cache OK)
#pragma unroll
    for (int k = 0; k < K; ++k)
        if (!fv[k]) v2[k] = *(const float2*)(emb_in + (size_t)cv[k] * D + 2 * lane);

    for (int t = 0; t < T_STEPS; ++t) {
        // mutable gathers: LLC-coherent, see state after step t-1's barrier B
        float2 u2 = aload8(out + (size_t)cu * D + 2 * lane);
#pragma unroll
        for (int k = 0; k < K; ++k)
            if (fv[k]) v2[k] = aload8(out + (size_t)cv[k] * D + 2 * lane);

        // next-step index/flag loads issue here, overlapping gather latency
        int  ncu = 0, ncv[K];
        uint nfv[K];
        if (t + 1 < T_STEPS) {
            const int nb = (t + 1) * B + b;
            ncu = u_idx[nb];
#pragma unroll
            for (int k = 0; k < K; ++k) ncv[k] = tgt_idx[nb * K + k];
#pragma unroll
            for (int k = 0; k < K; ++k) nfv[k] = SPARSE ? flags[ncv[k]] : 1u;
        } else {
#pragma unroll
            for (int k = 0; k < K; ++k) { ncv[k] = 0; nfv[k] = 1u; }
        }

        bar_arrive(ws_u, 2 * t);           // signals: my gathers are complete

        // err = sum_k g_k * v_k -- pure register work, hides rendezvous A
        float2 e2 = make_float2(0.f, 0.f);
#pragma unroll
        for (int k = 0; k < K; ++k) {
            const float s = wave_sum(u2.x * v2[k].x + u2.y * v2[k].y);
            const float f = 1.f / (1.f + __expf(-s));
            const float g = ALPHA * ((k == 0 ? 1.f : 0.f) - f);
            e2.x += g * v2[k].x;
            e2.y += g * v2[k].y;
        }

        bar_wait(ws_u, 2 * t);             // all gathers of step t done grid-wide

        float* urow = out + (size_t)cu * D + 2 * lane;
        atomicAdd(urow,     e2.x);         // RMW at LLC -> coherent
        atomicAdd(urow + 1, e2.y);

        if (t + 1 < T_STEPS) {
            bar_arrive(ws_u, 2 * t + 1);   // syncthreads drained the scatters
            // next step's immutable gathers hide rendezvous B
#pragma unroll
            for (int k = 0; k < K; ++k)
                if (!nfv[k]) v2[k] = *(const float2*)(emb_in + (size_t)ncv[k] * D + 2 * lane);
            bar_wait(ws_u, 2 * t + 1);     // all scatters of step t at LLC
        }
        // last step: kernel boundary is the barrier before normalize_k

        cu = ncu;
#pragma unroll
        for (int k = 0; k < K; ++k) { cv[k] = ncv[k]; fv[k] = nfv[k]; }
    }
}

// ---------------- final L2 row-normalize: full-BW streaming kernel -------------
template <bool SPARSE>
__global__ __launch_bounds__(256) void normalize_k(const float* __restrict__ emb_in,
                                                   float*       __restrict__ out,
                                                   const uint*  __restrict__ flags)
{
    const int wave = (blockIdx.x * 256 + threadIdx.x) >> 6;
    const int lane = threadIdx.x & 63;
    const int nw = gridDim.x * 4;
    for (int r0 = wave * 4; r0 < N_NODES; r0 += nw * 4) {
        uint4 f4 = SPARSE ? *(const uint4*)(flags + r0) : make_uint4(1u, 1u, 1u, 1u);
        const uint fl[4] = { f4.x, f4.y, f4.z, f4.w };
        float2 v[4];
#pragma unroll
        for (int j = 0; j < 4; ++j) {
            const float* src = fl[j] ? out : emb_in;   // wave-uniform branch
            v[j] = *(const float2*)(src + (size_t)(r0 + j) * D + 2 * lane);
        }
#pragma unroll
        for (int j = 0; j < 4; ++j) {
            const float ss  = wave_sum(v[j].x * v[j].x + v[j].y * v[j].y);
            const float inv = 1.f / fmaxf(sqrtf(ss), 1e-12f);
            *(float2*)(out + (size_t)(r0 + j) * D + 2 * lane) =
                make_float2(v[j].x * inv, v[j].y * inv);
        }
    }
}

extern "C" void kernel_launch(void* const* d_in, const int* in_sizes, int n_in,
                              void* d_out, int out_size, void* d_ws, size_t ws_size,
                              hipStream_t stream)
{
    const float* emb_in  = (const float*)d_in[0];
    const int*   u_idx   = (const int*)d_in[1];
    const int*   tgt_idx = (const int*)d_in[2];
    float*       out     = (float*)d_out;
    uint*        ws_u    = (uint*)d_ws;
    uint*        flags   = ws_u + FLAG_OFF;

    const bool sparse = ws_size >= SPARSE_BYTES;
    hipMemsetAsync(d_ws, 0, sparse ? SPARSE_BYTES : CNT_BYTES, stream);

    if (sparse) {
        prologue<true>  <<<1024, 256, 0, stream>>>(emb_in, u_idx, out, flags);
        line_loop<true> <<<LNBLK, LTPB, 0, stream>>>(emb_in, u_idx, tgt_idx, out, ws_u);
        normalize_k<true> <<<2048, 256, 0, stream>>>(emb_in, out, flags);
    } else {
        prologue<false>  <<<2048, 256, 0, stream>>>(emb_in, u_idx, out, flags);
        line_loop<false> <<<LNBLK, LTPB, 0, stream>>>(emb_in, u_idx, tgt_idx, out, ws_u);
        normalize_k<false> <<<2048, 256, 0, stream>>>(emb_in, out, flags);
    }
}